// Round 27
// baseline (86.890 us; speedup 1.0000x reference)
//
#include <hip/hip_runtime.h>
#include <cstdint>

#define T_STEPS 16384

// ---- workspace float offsets ----
#define WS_U     0
#define WS_V     256
#define WS_W1ZT  512
#define WS_PEN   2560
#define WS_A     2624
#define WS_W4T   2688
#define WS_W2T   3968
#define WS_W3T   36736
#define WS_DV    53120
#define WS_G     184192
#define WS_CONS  315264
#define WS_ABT   1363840
#define WS_A4LR  1888128
#define WS_H3LR  1920896
#define WS_END_F 2183040
#define WSB_NXT8 ((size_t)WS_END_F * 4)
#define WSB_CRX  (WSB_NXT8 + 131072 + 65536)   // int CRX[2048][24]

// k_prep grid: W2T(128) + W3T(32) + setup(1)
#define NB_PREP  161
// k_abdivg grid: ab(2048) + div(256) + gumbel(512)
#define AB_N     2048
#define DIVB     2048
#define GUMB     (DIVB + 256)     // 2304
#define NB_ABDG  (GUMB + 512)     // 2816

__device__ __forceinline__ unsigned int fn_compose(unsigned int hi, unsigned int lo) {
  unsigned int r = 0;
  #pragma unroll
  for (int x = 0; x < 8; ++x) {
    unsigned int m = (lo >> (3 * x)) & 7u;
    r |= ((hi >> (3 * m)) & 7u) << (3 * x);
  }
  return r;
}

// ---------------- prep: transposes + setup only ----------------
__global__ void __launch_bounds__(256) k_prep(
    const float* __restrict__ pa, const int* __restrict__ edge,
    const float* __restrict__ W1, const float* __restrict__ b1,
    const float* __restrict__ W2, const float* __restrict__ W3,
    const float* __restrict__ W4,
    float* __restrict__ ws) {
  int b = blockIdx.x, tid = threadIdx.x;
  if (b < 128) {            // W2T[k][j] = W2[j][k]
    int e = b * 256 + tid;
    int k = e >> 7, j = e & 127;
    ws[WS_W2T + e] = W2[j * 256 + k];
  } else if (b < 160) {     // W3T[j][i] = W3[i][j]
    int e = (b - 128) * 256 + tid;
    int i = e & 63, j = e >> 6;
    ws[WS_W3T + e] = W3[i * 128 + j];
  } else {                  // setup: U, V, W1ZT, W4T, PEN
    {
      int k = tid;
      float acc = b1[k];
      #pragma unroll
      for (int i = 0; i < 8; ++i) acc = fmaf(pa[i], W1[k * 17 + i], acc);
      ws[WS_U + k] = acc;
      ws[WS_V + k] = W1[k * 17 + 8];
    }
    for (int e = tid; e < 2048; e += 256) {
      int cc = e >> 8, k = e & 255;
      ws[WS_W1ZT + e] = W1[k * 17 + 9 + cc];
    }
    for (int e = tid; e < 512; e += 256) {
      int k = e >> 3, z = e & 7;
      ws[WS_W4T + e] = W4[z * 64 + k];
    }
    if (tid < 64) ws[WS_A + tid] = ((tid >> 3) == (tid & 7)) ? 1.0f : 0.0f;
    __syncthreads();
    if (tid == 0) {
      for (int e = 0; e < 16; ++e) {
        int aa = edge[e], bb = edge[16 + e];
        ws[WS_A + aa * 8 + bb] = 1.0f;
        ws[WS_A + bb * 8 + aa] = 1.0f;
      }
    }
    __syncthreads();
    if (tid < 64) ws[WS_PEN + tid] = 1000.0f * (1.0f - ws[WS_A + tid]);
  }
}

struct __align__(16) SmemDiv {
  float sD2h[64 * 64];   // 16KB half of D2
  float sudc[128], svdc[128];
  float part[3][8][64];
};
struct __align__(16) SmemAb {
  float au[256], av[256];
  float pa_[128], pb_[128];
  unsigned long long bal[4];
  unsigned long long bal2[2];
  float h2L[128], h2R[128];
  float h3pL[4][64], h3pR[4][64];
  float h3L[64], h3R[64];
  int d3, cnt, cnt2;
};
union SmemU {
  SmemDiv div;
  SmemAb ab;
};

// ---------------- ab (R24 body) + diversity (R20-proven) + gumbel, one launch ----------------
__global__ void __launch_bounds__(256) k_abdivg(
    const float* __restrict__ pa, const float* __restrict__ times,
    const float* __restrict__ gum,
    const float* __restrict__ u_, const float* __restrict__ v_,
    const float* __restrict__ w1zt, const float* __restrict__ w2t,
    const float* __restrict__ w3t, const float* __restrict__ w4t,
    const float* __restrict__ b2, const float* __restrict__ b3,
    const float* __restrict__ b4,
    const float* __restrict__ D1, const float* __restrict__ d1,
    const float* __restrict__ D2, const float* __restrict__ d2,
    const float* __restrict__ D3, const float* __restrict__ d3,
    float* __restrict__ ws, float* __restrict__ abt, int* __restrict__ crx,
    float* __restrict__ a4lr, float* __restrict__ h3lr) {
  __shared__ SmemU sm;
  int bid = blockIdx.x, tid = threadIdx.x;
  float last = times[T_STEPS - 1];

  if (bid < AB_N) {
    // ===== AB precompute (R24 measured-good body) =====
    int blk = bid;
    int c = blk >> 8, tile = blk & 255;
    float stL = (last > 0.0f) ? times[tile * 64] / last : 0.0f;
    float stR = (last > 0.0f) ? times[tile * 64 + 63] / last : 0.0f;
    {
      float uk = u_[tid] + w1zt[c * 256 + tid];
      float vk = v_[tid];
      float valL = fmaf(stL, vk, uk);
      float valR = fmaf(stR, vk, uk);
      float mn = fminf(valL, valR);
      float mx = fmaxf(valL, valR);
      bool act = (mn > 0.0f);
      bool cross = (!act) && (mx > 0.0f);
      sm.ab.au[tid] = act ? uk : 0.0f;
      sm.ab.av[tid] = act ? vk : 0.0f;
      unsigned long long bal = __ballot(cross);
      if ((tid & 63) == 0) sm.ab.bal[tid >> 6] = bal;
    }
    if (tid == 0) sm.ab.d3 = 0;
    __syncthreads();
    if (tid == 0) {
      int cnt = 0;
      int list8[8];
      #pragma unroll
      for (int i = 0; i < 8; ++i) list8[i] = 0;
      #pragma unroll
      for (int w = 0; w < 4; ++w) {
        unsigned long long m = sm.ab.bal[w];
        while (m) {
          int bit = __ffsll(m) - 1;
          if (cnt < 8) list8[cnt] = w * 64 + bit;
          ++cnt;
          m &= (m - 1);
        }
      }
      crx[blk * 24] = cnt;
      sm.ab.cnt = cnt;
      #pragma unroll
      for (int i = 0; i < 8; ++i) crx[blk * 24 + 1 + i] = list8[i];
    }
    {
      int j = tid & 127, half = tid >> 7;
      float A = 0.0f, B = 0.0f;
      const float* wrow = w2t + half * 128 * 128 + j;
      int kb = half * 128;
      #pragma unroll 4
      for (int kk = 0; kk < 128; ++kk) {
        float w = wrow[kk * 128];
        A = fmaf(sm.ab.au[kb + kk], w, A);
        B = fmaf(sm.ab.av[kb + kk], w, B);
      }
      if (half == 1) { sm.ab.pa_[j] = A; sm.ab.pb_[j] = B; }
      __syncthreads();
      bool jcross = false;
      if (half == 0) {
        float Af = A + sm.ab.pa_[j] + b2[j];
        float Bf = B + sm.ab.pb_[j];
        abt[(size_t)blk * 256 + j * 2]     = Af;
        abt[(size_t)blk * 256 + j * 2 + 1] = Bf;
        float preL = fmaf(stL, Bf, Af);
        float preR = fmaf(stR, Bf, Af);
        jcross = (preL > 0.0f) != (preR > 0.0f);
        sm.ab.h2L[j] = fmaxf(preL, 0.0f);
        sm.ab.h2R[j] = fmaxf(preR, 0.0f);
      }
      unsigned long long bal2 = __ballot(jcross);
      if ((tid & 63) == 0 && tid < 128) sm.ab.bal2[tid >> 6] = bal2;
    }
    __syncthreads();
    if (tid == 0) {
      int cnt2 = 0;
      int list8[8];
      #pragma unroll
      for (int i = 0; i < 8; ++i) list8[i] = 0;
      #pragma unroll
      for (int w = 0; w < 2; ++w) {
        unsigned long long m = sm.ab.bal2[w];
        while (m) {
          int bit = __ffsll(m) - 1;
          if (cnt2 < 8) list8[cnt2] = w * 64 + bit;
          ++cnt2;
          m &= (m - 1);
        }
      }
      crx[blk * 24 + 10] = cnt2;
      sm.ab.cnt2 = cnt2;
      #pragma unroll
      for (int i = 0; i < 8; ++i) crx[blk * 24 + 11 + i] = list8[i];
    }
    __syncthreads();
    {
      int i = tid & 63, jq = tid >> 6;
      float aL = (jq == 0) ? b3[i] : 0.0f;
      float aR = aL;
      int j0 = jq * 32;
      #pragma unroll 4
      for (int jj = 0; jj < 32; ++jj) {
        float w = w3t[(j0 + jj) * 64 + i];
        aL = fmaf(w, sm.ab.h2L[j0 + jj], aL);
        aR = fmaf(w, sm.ab.h2R[j0 + jj], aR);
      }
      sm.ab.h3pL[jq][i] = aL;
      sm.ab.h3pR[jq][i] = aR;
    }
    __syncthreads();
    if (tid < 64) {
      float preL = sm.ab.h3pL[0][tid] + sm.ab.h3pL[1][tid] + sm.ab.h3pL[2][tid] + sm.ab.h3pL[3][tid];
      float preR = sm.ab.h3pR[0][tid] + sm.ab.h3pR[1][tid] + sm.ab.h3pR[2][tid] + sm.ab.h3pR[3][tid];
      if ((preL > 0.0f) != (preR > 0.0f)) atomicOr(&sm.ab.d3, 1);
      sm.ab.h3L[tid] = fmaxf(preL, 0.0f);
      sm.ab.h3R[tid] = fmaxf(preR, 0.0f);
      h3lr[(size_t)blk * 128 + tid]      = preL;
      h3lr[(size_t)blk * 128 + 64 + tid] = preR;
    }
    __syncthreads();
    if (tid < 8) {
      float aL = b4[tid], aR = b4[tid];
      #pragma unroll 8
      for (int i = 0; i < 64; ++i) {
        float w = w4t[i * 8 + tid];
        aL = fmaf(w, sm.ab.h3L[i], aL);
        aR = fmaf(w, sm.ab.h3R[i], aR);
      }
      a4lr[blk * 16 + tid]     = aL;
      a4lr[blk * 16 + 8 + tid] = aR;
    }
    if (tid == 0) {
      int flag;
      if (sm.ab.cnt > 0 || sm.ab.cnt2 > 8) flag = 0;
      else if (sm.ab.cnt2 > 0 || sm.ab.d3) flag = 3;
      else flag = 1;
      crx[blk * 24 + 9] = flag;
    }
  } else if (bid < GUMB) {
    // ===== diversity (R20-proven half-staged variant) =====
    int db = bid - DIVB;
    int lane = tid & 63;
    int w = __builtin_amdgcn_readfirstlane(tid >> 6);
    int t = db * 64 + lane;
    float st = (last > 0.0f) ? times[t] / last : 0.0f;
    if (tid < 128) {
      float acc = d1[tid];
      #pragma unroll
      for (int i = 0; i < 8; ++i) acc = fmaf(pa[i], D1[tid * 9 + i], acc);
      sm.div.sudc[tid] = acc;
      sm.div.svdc[tid] = D1[tid * 9 + 8];
    }
    int j0 = __builtin_amdgcn_readfirstlane(w * 16);
    float accj[16];
    #pragma unroll
    for (int jj = 0; jj < 16; ++jj) accj[jj] = d2[j0 + jj];
    for (int half = 0; half < 2; ++half) {
      __syncthreads();
      #pragma unroll
      for (int r = 0; r < 4; ++r) {
        int e4 = r * 256 + tid;
        int j = e4 >> 4, kk4 = e4 & 15;
        ((float4*)sm.div.sD2h)[e4] =
            *(const float4*)(D2 + j * 128 + half * 64 + kk4 * 4);
      }
      __syncthreads();
      #pragma unroll 4
      for (int kk = 0; kk < 64; ++kk) {
        int k = half * 64 + kk;
        float h1 = fmaxf(fmaf(st, sm.div.svdc[k], sm.div.sudc[k]), 0.0f);
        #pragma unroll
        for (int jj = 0; jj < 16; ++jj)
          accj[jj] = fmaf(sm.div.sD2h[(j0 + jj) * 64 + kk], h1, accj[jj]);
      }
    }
    float dvp[8];
    #pragma unroll
    for (int z = 0; z < 8; ++z) dvp[z] = (w == 0) ? d3[z] : 0.0f;
    #pragma unroll
    for (int jj = 0; jj < 16; ++jj) {
      float h2 = fmaxf(accj[jj], 0.0f);
      #pragma unroll
      for (int z = 0; z < 8; ++z)
        dvp[z] = fmaf(D3[z * 64 + j0 + jj], h2, dvp[z]);
    }
    if (w > 0) {
      #pragma unroll
      for (int z = 0; z < 8; ++z) sm.div.part[w - 1][z][lane] = dvp[z];
    }
    __syncthreads();
    if (w == 0) {
      #pragma unroll
      for (int z = 0; z < 8; ++z) {
        float dvv = dvp[z] + sm.div.part[0][z][lane] + sm.div.part[1][z][lane] +
                    sm.div.part[2][z][lane];
        ws[WS_DV + t * 8 + z] = tanhf(dvv);
      }
    }
  } else {
    // ===== gumbels =====
    int e = (bid - GUMB) * 256 + tid;
    float uu = gum[e];
    ws[WS_G + e] = -logf(-logf(uu + 1e-20f) + 1e-20f);
  }
}

// ---------------- fused MLP: tiered; tier-1 skips cons stores ----------------
__global__ void __launch_bounds__(256, 4) k_mlp(
    const float* __restrict__ times,
    const float* __restrict__ u_, const float* __restrict__ v_,
    const float* __restrict__ w1zt, const float* __restrict__ w2t,
    const float* __restrict__ abt, const int* __restrict__ crx,
    const float* __restrict__ a4lr, const float* __restrict__ h3lr,
    const float* __restrict__ w3t, const float* __restrict__ w4t,
    const float* __restrict__ b2, const float* __restrict__ b3,
    const float* __restrict__ b4,
    const float* __restrict__ dv, const float* __restrict__ gt,
    const float* __restrict__ pen, const float* __restrict__ tau,
    float* __restrict__ cons_out, unsigned char* __restrict__ nxt_out) {
  __shared__ float part[3][8][64];  // 6KB
  __shared__ float s_w3[8192];      // 32KB (staged only when flag==0)
  __shared__ float s_ab[256];       // 1KB
  int tid = threadIdx.x;
  int lane = tid & 63;
  int iq = __builtin_amdgcn_readfirstlane(tid >> 6);
  int blk = blockIdx.x;
  int c = blk >> 8, tgrp = blk & 255;
  int t = tgrp * 64 + lane;
  int abase = blk * 256;
  int cbase = blk * 24;
  int flag = crx[cbase + 9];

  if (flag == 1) {
    if (iq == 0) {
      float frac = (float)lane * (1.0f / 63.0f);
      float a4[8];
      #pragma unroll
      for (int z = 0; z < 8; ++z) {
        float L = a4lr[blk * 16 + z];
        float R = a4lr[blk * 16 + 8 + z];
        a4[z] = fmaf(frac, R - L, L);
      }
      float4 dv0 = *(const float4*)(dv + (size_t)t * 8);
      float4 dv1 = *(const float4*)(dv + (size_t)t * 8 + 4);
      float4 g0  = *(const float4*)(gt + (size_t)t * 8);
      float4 g1  = *(const float4*)(gt + (size_t)t * 8 + 4);
      float dvv[8] = {dv0.x, dv0.y, dv0.z, dv0.w, dv1.x, dv1.y, dv1.z, dv1.w};
      float gv[8]  = {g0.x, g0.y, g0.z, g0.w, g1.x, g1.y, g1.z, g1.w};
      float sgn = (tau[0] > 0.0f) ? 1.0f : -1.0f;
      float best = 0.0f; int bz = 0;
      #pragma unroll
      for (int z = 0; z < 8; ++z) {
        float lg = fmaf(0.2f, dvv[z], a4[z]) - pen[c * 8 + z];
        float yv = (lg + gv[z]) * sgn;
        if (z == 0) { best = yv; bz = 0; }
        else if (yv > best) { best = yv; bz = z; }
      }
      // cons stores skipped: scangather recomputes tier-1 logits from a4lr
      nxt_out[t * 8 + c] = (unsigned char)bz;
    }
    return;
  }

  float last = times[T_STEPS - 1];
  float st = (last > 0.0f) ? times[t] / last : 0.0f;
  const float* w1c = w1zt + c * 256;
  int cnt = crx[cbase];
  int i0 = iq * 16;

  float acc[16];
  if (flag == 3) {
    float frac = (float)lane * (1.0f / 63.0f);
    #pragma unroll
    for (int i = 0; i < 16; ++i) {
      float L = h3lr[(size_t)blk * 128 + i0 + i];
      float R = h3lr[(size_t)blk * 128 + 64 + i0 + i];
      acc[i] = fmaf(frac, R - L, L);
    }
    int cnt2 = crx[cbase + 10];
    float stL = (last > 0.0f) ? times[tgrp * 64] / last : 0.0f;
    float stR = (last > 0.0f) ? times[tgrp * 64 + 63] / last : 0.0f;
    for (int q = 0; q < cnt2; ++q) {
      int j = crx[cbase + 11 + q];
      float A = abt[abase + j * 2];
      float B = abt[abase + j * 2 + 1];
      float preL = fmaf(stL, B, A);
      float preR = fmaf(stR, B, A);
      float rL = fmaxf(preL, 0.0f);
      float rR = fmaxf(preR, 0.0f);
      float pre = fmaf(st, B, A);
      float corr = fmaxf(pre, 0.0f) - fmaf(frac, rR - rL, rL);
      #pragma unroll
      for (int i = 0; i < 16; ++i)
        acc[i] = fmaf(corr, w3t[j * 64 + i0 + i], acc[i]);
    }
  } else {
    {
      const float4* w3v = (const float4*)w3t;
      float4* sw3 = (float4*)s_w3;
      #pragma unroll
      for (int r = 0; r < 8; ++r) sw3[r * 256 + tid] = w3v[r * 256 + tid];
      s_ab[tid] = abt[abase + tid];
    }
    __syncthreads();
    #pragma unroll
    for (int i = 0; i < 16; ++i) acc[i] = b3[i0 + i];

    if (cnt <= 8) {
      int kk[8];
      #pragma unroll
      for (int i = 0; i < 8; ++i) kk[i] = (i < cnt) ? crx[cbase + 1 + i] : 0;
      float hx[8];
      #pragma unroll
      for (int i = 0; i < 8; ++i)
        hx[i] = (i < cnt) ? fmaxf(fmaf(st, v_[kk[i]], u_[kk[i]] + w1c[kk[i]]), 0.0f) : 0.0f;
      #pragma unroll 2
      for (int j = 0; j < 128; ++j) {
        float2 ab = *(const float2*)(s_ab + j * 2);
        float h2p = fmaf(st, ab.y, ab.x);
        #pragma unroll
        for (int i = 0; i < 8; ++i)
          h2p = fmaf(hx[i], w2t[kk[i] * 128 + j], h2p);
        float h2 = fmaxf(h2p, 0.0f);
        const float4* w3p = (const float4*)(s_w3 + j * 64 + i0);
        float4 w0 = w3p[0], w1 = w3p[1], w2v = w3p[2], w3v = w3p[3];
        acc[0]  = fmaf(w0.x, h2, acc[0]);   acc[1]  = fmaf(w0.y, h2, acc[1]);
        acc[2]  = fmaf(w0.z, h2, acc[2]);   acc[3]  = fmaf(w0.w, h2, acc[3]);
        acc[4]  = fmaf(w1.x, h2, acc[4]);   acc[5]  = fmaf(w1.y, h2, acc[5]);
        acc[6]  = fmaf(w1.z, h2, acc[6]);   acc[7]  = fmaf(w1.w, h2, acc[7]);
        acc[8]  = fmaf(w2v.x, h2, acc[8]);  acc[9]  = fmaf(w2v.y, h2, acc[9]);
        acc[10] = fmaf(w2v.z, h2, acc[10]); acc[11] = fmaf(w2v.w, h2, acc[11]);
        acc[12] = fmaf(w3v.x, h2, acc[12]); acc[13] = fmaf(w3v.y, h2, acc[13]);
        acc[14] = fmaf(w3v.z, h2, acc[14]); acc[15] = fmaf(w3v.w, h2, acc[15]);
      }
    } else {
      for (int j = 0; j < 128; ++j) {
        float h2p = b2[j];
        for (int k = 0; k < 256; ++k) {
          float h1 = fmaxf(fmaf(st, v_[k], u_[k] + w1c[k]), 0.0f);
          h2p = fmaf(w2t[k * 128 + j], h1, h2p);
        }
        float h2 = fmaxf(h2p, 0.0f);
        #pragma unroll
        for (int i = 0; i < 16; ++i)
          acc[i] = fmaf(s_w3[j * 64 + i0 + i], h2, acc[i]);
      }
    }
  }

  float p[8];
  #pragma unroll
  for (int z = 0; z < 8; ++z) p[z] = (iq == 0) ? b4[z] : 0.0f;
  #pragma unroll 4
  for (int i = 0; i < 16; ++i) {
    float h3 = fmaxf(acc[i], 0.0f);
    #pragma unroll
    for (int z = 0; z < 8; ++z)
      p[z] = fmaf(w4t[(i0 + i) * 8 + z], h3, p[z]);
  }
  if (iq > 0) {
    #pragma unroll
    for (int z = 0; z < 8; ++z) part[iq - 1][z][lane] = p[z];
  }
  __syncthreads();
  if (iq == 0) {
    float a4[8];
    #pragma unroll
    for (int z = 0; z < 8; ++z)
      a4[z] = p[z] + part[0][z][lane] + part[1][z][lane] + part[2][z][lane];
    float4 dv0 = *(const float4*)(dv + (size_t)t * 8);
    float4 dv1 = *(const float4*)(dv + (size_t)t * 8 + 4);
    float4 g0  = *(const float4*)(gt + (size_t)t * 8);
    float4 g1  = *(const float4*)(gt + (size_t)t * 8 + 4);
    float dvv[8] = {dv0.x, dv0.y, dv0.z, dv0.w, dv1.x, dv1.y, dv1.z, dv1.w};
    float gv[8]  = {g0.x, g0.y, g0.z, g0.w, g1.x, g1.y, g1.z, g1.w};
    float sgn = (tau[0] > 0.0f) ? 1.0f : -1.0f;
    float cons[8];
    float best = 0.0f; int bz = 0;
    #pragma unroll
    for (int z = 0; z < 8; ++z) {
      float lg = fmaf(0.2f, dvv[z], a4[z]) - pen[c * 8 + z];
      cons[z] = lg;
      float yv = (lg + gv[z]) * sgn;
      if (z == 0) { best = yv; bz = 0; }
      else if (yv > best) { best = yv; bz = z; }
    }
    float* co = cons_out + ((size_t)t * 8 + c) * 8;
    *(float4*)co = make_float4(cons[0], cons[1], cons[2], cons[3]);
    *(float4*)(co + 4) = make_float4(cons[4], cons[5], cons[6], cons[7]);
    nxt_out[t * 8 + c] = (unsigned char)bz;
  }
}

// ---------------- scan + gather fused (redundant scan) + tier-1 recompute ----------------
__global__ void __launch_bounds__(1024) k_scangather(
    const float* __restrict__ ws, const int* __restrict__ crx,
    const float* __restrict__ a4lr, const float* __restrict__ dv,
    const float* __restrict__ pen, float* __restrict__ d_out) {
  __shared__ unsigned int sc[1024];
  __shared__ unsigned char cur_s[128];
  int tid = threadIdx.x;
  int bid = blockIdx.x;                  // 0..127
  const unsigned char* nxt8 = (const unsigned char*)ws + WSB_NXT8;
  const unsigned int IDENT = 0x00FAC688u;
  unsigned int f[16];
  int t0 = tid * 16;
  unsigned int F = IDENT;
  #pragma unroll
  for (int i = 0; i < 16; ++i) {
    uint2 b = *(const uint2*)(nxt8 + (size_t)(t0 + i) * 8);
    unsigned int fn = 0;
    #pragma unroll
    for (int q = 0; q < 4; ++q) fn |= ((b.x >> (8 * q)) & 7u) << (3 * q);
    #pragma unroll
    for (int q = 0; q < 4; ++q) fn |= ((b.y >> (8 * q)) & 7u) << (3 * (q + 4));
    f[i] = fn;
    F = fn_compose(fn, F);
  }
  sc[tid] = F;
  __syncthreads();
  #pragma unroll
  for (int d = 1; d < 1024; d <<= 1) {
    unsigned int v = sc[tid];
    unsigned int p = (tid >= d) ? sc[tid - d] : 0u;
    unsigned int nv = (tid >= d) ? fn_compose(v, p) : v;
    __syncthreads();
    sc[tid] = nv;
    __syncthreads();
  }
  unsigned int E = (tid == 0) ? IDENT : sc[tid - 1];
  unsigned int state = E & 7u;
  bool mine = (tid >> 3) == bid;
  #pragma unroll
  for (int i = 0; i < 16; ++i) {
    int tt = t0 + i;
    unsigned int nx = (f[i] >> (3 * state)) & 7u;
    if (mine) {
      cur_s[tt - bid * 128] = (unsigned char)state;
      d_out[131072 + tt] = (float)nx;
    }
    state = nx;
  }
  __syncthreads();
  int idx = bid * 1024 + tid;              // < 131072
  int t = idx >> 3, z = idx & 7;
  int cur = (int)cur_s[t - bid * 128];
  int tile = t >> 6;
  int blk2 = cur * 256 + tile;
  int flag = crx[blk2 * 24 + 9];
  float val;
  if (flag == 1) {
    // recompute tier-1 logit (bit-identical to mlp's arithmetic)
    float frac = (float)(t & 63) * (1.0f / 63.0f);
    float L = a4lr[blk2 * 16 + z];
    float R = a4lr[blk2 * 16 + 8 + z];
    float a4 = fmaf(frac, R - L, L);
    val = fmaf(0.2f, dv[(size_t)t * 8 + z], a4) - pen[cur * 8 + z];
  } else {
    val = ws[WS_CONS + ((size_t)t * 8 + cur) * 8 + z];
  }
  d_out[idx] = val;
}

extern "C" void kernel_launch(void* const* d_in, const int* in_sizes, int n_in,
                              void* d_out, int out_size, void* d_ws, size_t ws_size,
                              hipStream_t stream) {
  const float* pa    = (const float*)d_in[0];
  const float* times = (const float*)d_in[1];
  const float* gum   = (const float*)d_in[2];
  const int*   edge  = (const int*)d_in[3];
  const float* W1  = (const float*)d_in[4];
  const float* b1  = (const float*)d_in[5];
  const float* W2  = (const float*)d_in[6];
  const float* b2  = (const float*)d_in[7];
  const float* W3  = (const float*)d_in[8];
  const float* b3  = (const float*)d_in[9];
  const float* W4  = (const float*)d_in[10];
  const float* b4  = (const float*)d_in[11];
  const float* D1  = (const float*)d_in[12];
  const float* d1v = (const float*)d_in[13];
  const float* D2  = (const float*)d_in[14];
  const float* d2v = (const float*)d_in[15];
  const float* D3  = (const float*)d_in[16];
  const float* d3v = (const float*)d_in[17];
  const float* tau = (const float*)d_in[18];
  float* ws = (float*)d_ws;
  float* out = (float*)d_out;
  int* crx = (int*)((char*)d_ws + WSB_CRX);

  k_prep<<<NB_PREP, 256, 0, stream>>>(pa, edge, W1, b1, W2, W3, W4, ws);
  k_abdivg<<<NB_ABDG, 256, 0, stream>>>(pa, times, gum,
                                        ws + WS_U, ws + WS_V, ws + WS_W1ZT,
                                        ws + WS_W2T, ws + WS_W3T, ws + WS_W4T,
                                        b2, b3, b4, D1, d1v, D2, d2v, D3, d3v,
                                        ws, ws + WS_ABT, crx,
                                        ws + WS_A4LR, ws + WS_H3LR);
  k_mlp<<<2048, 256, 0, stream>>>(times, ws + WS_U, ws + WS_V, ws + WS_W1ZT,
                                  ws + WS_W2T, ws + WS_ABT, crx,
                                  ws + WS_A4LR, ws + WS_H3LR,
                                  ws + WS_W3T, ws + WS_W4T, b2, b3, b4,
                                  ws + WS_DV, ws + WS_G, ws + WS_PEN, tau,
                                  ws + WS_CONS, (unsigned char*)ws + WSB_NXT8);
  k_scangather<<<128, 1024, 0, stream>>>(ws, crx, ws + WS_A4LR, ws + WS_DV,
                                         ws + WS_PEN, out);
}

// Round 28
// 78.852 us; speedup vs baseline: 1.1019x; 1.1019x over previous
//
#include <hip/hip_runtime.h>
#include <cstdint>

#define T_STEPS 16384

// ---- workspace float offsets ----
#define WS_U     0
#define WS_V     256
#define WS_W1ZT  512
#define WS_PEN   2560
#define WS_A     2624
#define WS_W4T   2688
#define WS_W2T   3968
#define WS_W3T   36736
#define WS_DV    53120
#define WS_G     184192
#define WS_CONS  315264
#define WS_ABT   1363840
#define WS_A4LR  1888128
#define WS_H3LR  1920896
#define WS_END_F 2183040
#define WSB_NXT8 ((size_t)WS_END_F * 4)
#define WSB_CUR  (WSB_NXT8 + 131072)
#define WSB_CRX  (WSB_CUR + 65536)    // int CRX[2048][24]

// k_prepdiv grid layout
#define PB_DIV   0
#define PB_W2T   256
#define PB_W3T   (PB_W2T + 128)    // 384
#define PB_GUM   (PB_W3T + 32)     // 416
#define PB_SETUP (PB_GUM + 512)    // 928
#define NB_PREP  (PB_SETUP + 1)    // 929

__device__ __forceinline__ unsigned int fn_compose(unsigned int hi, unsigned int lo) {
  unsigned int r = 0;
  #pragma unroll
  for (int x = 0; x < 8; ++x) {
    unsigned int m = (lo >> (3 * x)) & 7u;
    r |= ((hi >> (3 * m)) & 7u) << (3 * x);
  }
  return r;
}

// ---------------- prep+div (R25 measured-good, unchanged) ----------------
__global__ void __launch_bounds__(256) k_prepdiv(
    const float* __restrict__ pa, const float* __restrict__ times,
    const float* __restrict__ gum, const int* __restrict__ edge,
    const float* __restrict__ W1, const float* __restrict__ b1,
    const float* __restrict__ W2, const float* __restrict__ W3,
    const float* __restrict__ W4,
    const float* __restrict__ D1, const float* __restrict__ d1,
    const float* __restrict__ D2, const float* __restrict__ d2,
    const float* __restrict__ D3, const float* __restrict__ d3,
    float* __restrict__ ws) {
  __shared__ float sD2[64 * 128];   // 32KB
  __shared__ float sudc[128], svdc[128];
  __shared__ float part[3][8][64];  // 6KB
  int b = blockIdx.x, tid = threadIdx.x;
  if (b < PB_W2T) {
    int lane = tid & 63;
    int w = __builtin_amdgcn_readfirstlane(tid >> 6);
    int t = b * 64 + lane;
    float last = times[T_STEPS - 1];
    float st = (last > 0.0f) ? times[t] / last : 0.0f;
    #pragma unroll
    for (int i = 0; i < 8; ++i)
      ((float4*)sD2)[i * 256 + tid] = ((const float4*)D2)[i * 256 + tid];
    if (tid < 128) {
      float acc = d1[tid];
      #pragma unroll
      for (int i = 0; i < 8; ++i) acc = fmaf(pa[i], D1[tid * 9 + i], acc);
      sudc[tid] = acc;
      svdc[tid] = D1[tid * 9 + 8];
    }
    __syncthreads();
    int j0 = __builtin_amdgcn_readfirstlane(w * 16);
    float accj[16];
    #pragma unroll
    for (int jj = 0; jj < 16; ++jj) accj[jj] = d2[j0 + jj];
    #pragma unroll 4
    for (int k = 0; k < 128; ++k) {
      float h1 = fmaxf(fmaf(st, svdc[k], sudc[k]), 0.0f);
      #pragma unroll
      for (int jj = 0; jj < 16; ++jj)
        accj[jj] = fmaf(sD2[(j0 + jj) * 128 + k], h1, accj[jj]);
    }
    float dvp[8];
    #pragma unroll
    for (int z = 0; z < 8; ++z) dvp[z] = (w == 0) ? d3[z] : 0.0f;
    #pragma unroll
    for (int jj = 0; jj < 16; ++jj) {
      float h2 = fmaxf(accj[jj], 0.0f);
      #pragma unroll
      for (int z = 0; z < 8; ++z)
        dvp[z] = fmaf(D3[z * 64 + j0 + jj], h2, dvp[z]);
    }
    if (w > 0) {
      #pragma unroll
      for (int z = 0; z < 8; ++z) part[w - 1][z][lane] = dvp[z];
    }
    __syncthreads();
    if (w == 0) {
      #pragma unroll
      for (int z = 0; z < 8; ++z) {
        float dvv = dvp[z] + part[0][z][lane] + part[1][z][lane] + part[2][z][lane];
        ws[WS_DV + t * 8 + z] = tanhf(dvv);
      }
    }
  } else if (b < PB_W3T) {
    int e = (b - PB_W2T) * 256 + tid;
    int k = e >> 7, j = e & 127;
    ws[WS_W2T + e] = W2[j * 256 + k];
  } else if (b < PB_GUM) {
    int e = (b - PB_W3T) * 256 + tid;
    int i = e & 63, j = e >> 6;
    ws[WS_W3T + e] = W3[i * 128 + j];
  } else if (b < PB_SETUP) {
    int e = (b - PB_GUM) * 256 + tid;
    float uu = gum[e];
    ws[WS_G + e] = -logf(-logf(uu + 1e-20f) + 1e-20f);
  } else {
    {
      int k = tid;
      float acc = b1[k];
      #pragma unroll
      for (int i = 0; i < 8; ++i) acc = fmaf(pa[i], W1[k * 17 + i], acc);
      ws[WS_U + k] = acc;
      ws[WS_V + k] = W1[k * 17 + 8];
    }
    for (int e = tid; e < 2048; e += 256) {
      int cc = e >> 8, k = e & 255;
      ws[WS_W1ZT + e] = W1[k * 17 + 9 + cc];
    }
    for (int e = tid; e < 512; e += 256) {
      int k = e >> 3, z = e & 7;
      ws[WS_W4T + e] = W4[z * 64 + k];
    }
    if (tid < 64) ws[WS_A + tid] = ((tid >> 3) == (tid & 7)) ? 1.0f : 0.0f;
    __syncthreads();
    if (tid == 0) {
      for (int e = 0; e < 16; ++e) {
        int aa = edge[e], bb = edge[16 + e];
        ws[WS_A + aa * 8 + bb] = 1.0f;
        ws[WS_A + bb * 8 + aa] = 1.0f;
      }
    }
    __syncthreads();
    if (tid < 64) ws[WS_PEN + tid] = 1000.0f * (1.0f - ws[WS_A + tid]);
  }
}

// ---------------- AB precompute + crossing lists + 3-tier flag (R25, unchanged) ----------------
__global__ void __launch_bounds__(256) k_ab4(
    const float* __restrict__ times,
    const float* __restrict__ u_, const float* __restrict__ v_,
    const float* __restrict__ w1zt, const float* __restrict__ w2t,
    const float* __restrict__ w3t, const float* __restrict__ w4t,
    const float* __restrict__ b2, const float* __restrict__ b3,
    const float* __restrict__ b4,
    float* __restrict__ abt, int* __restrict__ crx,
    float* __restrict__ a4lr, float* __restrict__ h3lr) {
  __shared__ float s_au[256], s_av[256];
  __shared__ float s_pa[128], s_pb[128];
  __shared__ unsigned long long s_bal[4];
  __shared__ unsigned long long s_bal2[2];
  __shared__ float s_h2L[128], s_h2R[128];
  __shared__ float s_h3pL[4][64], s_h3pR[4][64];
  __shared__ float s_h3L[64], s_h3R[64];
  __shared__ int s_d3, s_cnt, s_cnt2;
  int blk = blockIdx.x;
  int c = blk >> 8, tile = blk & 255;
  int tid = threadIdx.x;
  float last = times[T_STEPS - 1];
  float stL = (last > 0.0f) ? times[tile * 64] / last : 0.0f;
  float stR = (last > 0.0f) ? times[tile * 64 + 63] / last : 0.0f;
  {
    float uk = u_[tid] + w1zt[c * 256 + tid];
    float vk = v_[tid];
    float valL = fmaf(stL, vk, uk);
    float valR = fmaf(stR, vk, uk);
    float mn = fminf(valL, valR);
    float mx = fmaxf(valL, valR);
    bool act = (mn > 0.0f);
    bool cross = (!act) && (mx > 0.0f);
    s_au[tid] = act ? uk : 0.0f;
    s_av[tid] = act ? vk : 0.0f;
    unsigned long long bal = __ballot(cross);
    if ((tid & 63) == 0) s_bal[tid >> 6] = bal;
  }
  if (tid == 0) s_d3 = 0;
  __syncthreads();
  if (tid == 0) {
    int cnt = 0;
    int list8[8];
    #pragma unroll
    for (int i = 0; i < 8; ++i) list8[i] = 0;
    #pragma unroll
    for (int w = 0; w < 4; ++w) {
      unsigned long long m = s_bal[w];
      while (m) {
        int bit = __ffsll(m) - 1;
        if (cnt < 8) list8[cnt] = w * 64 + bit;
        ++cnt;
        m &= (m - 1);
      }
    }
    crx[blk * 24] = cnt;
    s_cnt = cnt;
    #pragma unroll
    for (int i = 0; i < 8; ++i) crx[blk * 24 + 1 + i] = list8[i];
  }
  {
    int j = tid & 127, half = tid >> 7;
    float A = 0.0f, B = 0.0f;
    const float* wrow = w2t + half * 128 * 128 + j;
    int kb = half * 128;
    #pragma unroll 4
    for (int kk = 0; kk < 128; ++kk) {
      float w = wrow[kk * 128];
      A = fmaf(s_au[kb + kk], w, A);
      B = fmaf(s_av[kb + kk], w, B);
    }
    if (half == 1) { s_pa[j] = A; s_pb[j] = B; }
    __syncthreads();
    bool jcross = false;
    if (half == 0) {
      float Af = A + s_pa[j] + b2[j];
      float Bf = B + s_pb[j];
      abt[(size_t)blk * 256 + j * 2]     = Af;
      abt[(size_t)blk * 256 + j * 2 + 1] = Bf;
      float preL = fmaf(stL, Bf, Af);
      float preR = fmaf(stR, Bf, Af);
      jcross = (preL > 0.0f) != (preR > 0.0f);
      s_h2L[j] = fmaxf(preL, 0.0f);
      s_h2R[j] = fmaxf(preR, 0.0f);
    }
    unsigned long long bal2 = __ballot(jcross);
    if ((tid & 63) == 0 && tid < 128) s_bal2[tid >> 6] = bal2;
  }
  __syncthreads();
  if (tid == 0) {
    int cnt2 = 0;
    int list8[8];
    #pragma unroll
    for (int i = 0; i < 8; ++i) list8[i] = 0;
    #pragma unroll
    for (int w = 0; w < 2; ++w) {
      unsigned long long m = s_bal2[w];
      while (m) {
        int bit = __ffsll(m) - 1;
        if (cnt2 < 8) list8[cnt2] = w * 64 + bit;
        ++cnt2;
        m &= (m - 1);
      }
    }
    crx[blk * 24 + 10] = cnt2;
    s_cnt2 = cnt2;
    #pragma unroll
    for (int i = 0; i < 8; ++i) crx[blk * 24 + 11 + i] = list8[i];
  }
  __syncthreads();
  {
    int i = tid & 63, jq = tid >> 6;
    float aL = (jq == 0) ? b3[i] : 0.0f;
    float aR = aL;
    int j0 = jq * 32;
    #pragma unroll 4
    for (int jj = 0; jj < 32; ++jj) {
      float w = w3t[(j0 + jj) * 64 + i];
      aL = fmaf(w, s_h2L[j0 + jj], aL);
      aR = fmaf(w, s_h2R[j0 + jj], aR);
    }
    s_h3pL[jq][i] = aL;
    s_h3pR[jq][i] = aR;
  }
  __syncthreads();
  if (tid < 64) {
    float preL = s_h3pL[0][tid] + s_h3pL[1][tid] + s_h3pL[2][tid] + s_h3pL[3][tid];
    float preR = s_h3pR[0][tid] + s_h3pR[1][tid] + s_h3pR[2][tid] + s_h3pR[3][tid];
    if ((preL > 0.0f) != (preR > 0.0f)) atomicOr(&s_d3, 1);
    s_h3L[tid] = fmaxf(preL, 0.0f);
    s_h3R[tid] = fmaxf(preR, 0.0f);
    h3lr[(size_t)blk * 128 + tid]      = preL;
    h3lr[(size_t)blk * 128 + 64 + tid] = preR;
  }
  __syncthreads();
  if (tid < 8) {
    float aL = b4[tid], aR = b4[tid];
    #pragma unroll 8
    for (int i = 0; i < 64; ++i) {
      float w = w4t[i * 8 + tid];
      aL = fmaf(w, s_h3L[i], aL);
      aR = fmaf(w, s_h3R[i], aR);
    }
    a4lr[blk * 16 + tid]     = aL;
    a4lr[blk * 16 + 8 + tid] = aR;
  }
  if (tid == 0) {
    int flag;
    if (s_cnt > 0 || s_cnt2 > 8) flag = 0;
    else if (s_cnt2 > 0 || s_d3) flag = 3;
    else flag = 1;
    crx[blk * 24 + 9] = flag;
  }
}

// ---------------- fused MLP: tiered; exact LDS-staged; tier-1 skips cons stores ----------------
__global__ void __launch_bounds__(256, 4) k_mlp(
    const float* __restrict__ times,
    const float* __restrict__ u_, const float* __restrict__ v_,
    const float* __restrict__ w1zt, const float* __restrict__ w2t,
    const float* __restrict__ abt, const int* __restrict__ crx,
    const float* __restrict__ a4lr, const float* __restrict__ h3lr,
    const float* __restrict__ w3t, const float* __restrict__ w4t,
    const float* __restrict__ b2, const float* __restrict__ b3,
    const float* __restrict__ b4,
    const float* __restrict__ dv, const float* __restrict__ gt,
    const float* __restrict__ pen, const float* __restrict__ tau,
    float* __restrict__ cons_out, unsigned char* __restrict__ nxt_out) {
  __shared__ float part[3][8][64];  // 6KB
  __shared__ float s_w3[8192];      // 32KB (staged only when flag==0)
  __shared__ float s_ab[256];       // 1KB
  int tid = threadIdx.x;
  int lane = tid & 63;
  int iq = __builtin_amdgcn_readfirstlane(tid >> 6);
  int blk = blockIdx.x;
  int c = blk >> 8, tgrp = blk & 255;
  int t = tgrp * 64 + lane;
  int abase = blk * 256;
  int cbase = blk * 24;
  int flag = crx[cbase + 9];

  if (flag == 1) {
    if (iq == 0) {
      float frac = (float)lane * (1.0f / 63.0f);
      float a4[8];
      #pragma unroll
      for (int z = 0; z < 8; ++z) {
        float L = a4lr[blk * 16 + z];
        float R = a4lr[blk * 16 + 8 + z];
        a4[z] = fmaf(frac, R - L, L);
      }
      float4 dv0 = *(const float4*)(dv + (size_t)t * 8);
      float4 dv1 = *(const float4*)(dv + (size_t)t * 8 + 4);
      float4 g0  = *(const float4*)(gt + (size_t)t * 8);
      float4 g1  = *(const float4*)(gt + (size_t)t * 8 + 4);
      float dvv[8] = {dv0.x, dv0.y, dv0.z, dv0.w, dv1.x, dv1.y, dv1.z, dv1.w};
      float gv[8]  = {g0.x, g0.y, g0.z, g0.w, g1.x, g1.y, g1.z, g1.w};
      float sgn = (tau[0] > 0.0f) ? 1.0f : -1.0f;
      float best = 0.0f; int bz = 0;
      #pragma unroll
      for (int z = 0; z < 8; ++z) {
        float lg = fmaf(0.2f, dvv[z], a4[z]) - pen[c * 8 + z];
        float yv = (lg + gv[z]) * sgn;
        if (z == 0) { best = yv; bz = 0; }
        else if (yv > best) { best = yv; bz = z; }
      }
      // cons stores skipped: scangather recomputes tier-1 logits
      nxt_out[t * 8 + c] = (unsigned char)bz;
    }
    return;
  }

  float last = times[T_STEPS - 1];
  float st = (last > 0.0f) ? times[t] / last : 0.0f;
  const float* w1c = w1zt + c * 256;
  int cnt = crx[cbase];
  int i0 = iq * 16;

  float acc[16];
  if (flag == 3) {
    float frac = (float)lane * (1.0f / 63.0f);
    #pragma unroll
    for (int i = 0; i < 16; ++i) {
      float L = h3lr[(size_t)blk * 128 + i0 + i];
      float R = h3lr[(size_t)blk * 128 + 64 + i0 + i];
      acc[i] = fmaf(frac, R - L, L);
    }
    int cnt2 = crx[cbase + 10];
    float stL = (last > 0.0f) ? times[tgrp * 64] / last : 0.0f;
    float stR = (last > 0.0f) ? times[tgrp * 64 + 63] / last : 0.0f;
    for (int q = 0; q < cnt2; ++q) {
      int j = crx[cbase + 11 + q];
      float A = abt[abase + j * 2];
      float B = abt[abase + j * 2 + 1];
      float preL = fmaf(stL, B, A);
      float preR = fmaf(stR, B, A);
      float rL = fmaxf(preL, 0.0f);
      float rR = fmaxf(preR, 0.0f);
      float pre = fmaf(st, B, A);
      float corr = fmaxf(pre, 0.0f) - fmaf(frac, rR - rL, rL);
      #pragma unroll
      for (int i = 0; i < 16; ++i)
        acc[i] = fmaf(corr, w3t[j * 64 + i0 + i], acc[i]);
    }
  } else {
    {
      const float4* w3v = (const float4*)w3t;
      float4* sw3 = (float4*)s_w3;
      #pragma unroll
      for (int r = 0; r < 8; ++r) sw3[r * 256 + tid] = w3v[r * 256 + tid];
      s_ab[tid] = abt[abase + tid];
    }
    __syncthreads();
    #pragma unroll
    for (int i = 0; i < 16; ++i) acc[i] = b3[i0 + i];

    if (cnt <= 8) {
      int kk[8];
      #pragma unroll
      for (int i = 0; i < 8; ++i) kk[i] = (i < cnt) ? crx[cbase + 1 + i] : 0;
      float hx[8];
      #pragma unroll
      for (int i = 0; i < 8; ++i)
        hx[i] = (i < cnt) ? fmaxf(fmaf(st, v_[kk[i]], u_[kk[i]] + w1c[kk[i]]), 0.0f) : 0.0f;
      #pragma unroll 2
      for (int j = 0; j < 128; ++j) {
        float2 ab = *(const float2*)(s_ab + j * 2);
        float h2p = fmaf(st, ab.y, ab.x);
        #pragma unroll
        for (int i = 0; i < 8; ++i)
          h2p = fmaf(hx[i], w2t[kk[i] * 128 + j], h2p);
        float h2 = fmaxf(h2p, 0.0f);
        const float4* w3p = (const float4*)(s_w3 + j * 64 + i0);
        float4 w0 = w3p[0], w1 = w3p[1], w2v = w3p[2], w3v = w3p[3];
        acc[0]  = fmaf(w0.x, h2, acc[0]);   acc[1]  = fmaf(w0.y, h2, acc[1]);
        acc[2]  = fmaf(w0.z, h2, acc[2]);   acc[3]  = fmaf(w0.w, h2, acc[3]);
        acc[4]  = fmaf(w1.x, h2, acc[4]);   acc[5]  = fmaf(w1.y, h2, acc[5]);
        acc[6]  = fmaf(w1.z, h2, acc[6]);   acc[7]  = fmaf(w1.w, h2, acc[7]);
        acc[8]  = fmaf(w2v.x, h2, acc[8]);  acc[9]  = fmaf(w2v.y, h2, acc[9]);
        acc[10] = fmaf(w2v.z, h2, acc[10]); acc[11] = fmaf(w2v.w, h2, acc[11]);
        acc[12] = fmaf(w3v.x, h2, acc[12]); acc[13] = fmaf(w3v.y, h2, acc[13]);
        acc[14] = fmaf(w3v.z, h2, acc[14]); acc[15] = fmaf(w3v.w, h2, acc[15]);
      }
    } else {
      for (int j = 0; j < 128; ++j) {
        float h2p = b2[j];
        for (int k = 0; k < 256; ++k) {
          float h1 = fmaxf(fmaf(st, v_[k], u_[k] + w1c[k]), 0.0f);
          h2p = fmaf(w2t[k * 128 + j], h1, h2p);
        }
        float h2 = fmaxf(h2p, 0.0f);
        #pragma unroll
        for (int i = 0; i < 16; ++i)
          acc[i] = fmaf(s_w3[j * 64 + i0 + i], h2, acc[i]);
      }
    }
  }

  float p[8];
  #pragma unroll
  for (int z = 0; z < 8; ++z) p[z] = (iq == 0) ? b4[z] : 0.0f;
  #pragma unroll 4
  for (int i = 0; i < 16; ++i) {
    float h3 = fmaxf(acc[i], 0.0f);
    #pragma unroll
    for (int z = 0; z < 8; ++z)
      p[z] = fmaf(w4t[(i0 + i) * 8 + z], h3, p[z]);
  }
  if (iq > 0) {
    #pragma unroll
    for (int z = 0; z < 8; ++z) part[iq - 1][z][lane] = p[z];
  }
  __syncthreads();
  if (iq == 0) {
    float a4[8];
    #pragma unroll
    for (int z = 0; z < 8; ++z)
      a4[z] = p[z] + part[0][z][lane] + part[1][z][lane] + part[2][z][lane];
    float4 dv0 = *(const float4*)(dv + (size_t)t * 8);
    float4 dv1 = *(const float4*)(dv + (size_t)t * 8 + 4);
    float4 g0  = *(const float4*)(gt + (size_t)t * 8);
    float4 g1  = *(const float4*)(gt + (size_t)t * 8 + 4);
    float dvv[8] = {dv0.x, dv0.y, dv0.z, dv0.w, dv1.x, dv1.y, dv1.z, dv1.w};
    float gv[8]  = {g0.x, g0.y, g0.z, g0.w, g1.x, g1.y, g1.z, g1.w};
    float sgn = (tau[0] > 0.0f) ? 1.0f : -1.0f;
    float cons[8];
    float best = 0.0f; int bz = 0;
    #pragma unroll
    for (int z = 0; z < 8; ++z) {
      float lg = fmaf(0.2f, dvv[z], a4[z]) - pen[c * 8 + z];
      cons[z] = lg;
      float yv = (lg + gv[z]) * sgn;
      if (z == 0) { best = yv; bz = 0; }
      else if (yv > best) { best = yv; bz = z; }
    }
    float* co = cons_out + ((size_t)t * 8 + c) * 8;
    *(float4*)co = make_float4(cons[0], cons[1], cons[2], cons[3]);
    *(float4*)(co + 4) = make_float4(cons[4], cons[5], cons[6], cons[7]);
    nxt_out[t * 8 + c] = (unsigned char)bz;
  }
}

// ---------------- scan + gather fused (redundant scan) + tier-1 recompute ----------------
__global__ void __launch_bounds__(1024) k_scangather(
    const float* __restrict__ ws, const int* __restrict__ crx,
    const float* __restrict__ a4lr, const float* __restrict__ dv,
    const float* __restrict__ pen, float* __restrict__ d_out) {
  __shared__ unsigned int sc[1024];
  __shared__ unsigned char cur_s[128];
  int tid = threadIdx.x;
  int bid = blockIdx.x;                  // 0..127
  const unsigned char* nxt8 = (const unsigned char*)ws + WSB_NXT8;
  const unsigned int IDENT = 0x00FAC688u;
  unsigned int f[16];
  int t0 = tid * 16;
  unsigned int F = IDENT;
  #pragma unroll
  for (int i = 0; i < 16; ++i) {
    uint2 b = *(const uint2*)(nxt8 + (size_t)(t0 + i) * 8);
    unsigned int fn = 0;
    #pragma unroll
    for (int q = 0; q < 4; ++q) fn |= ((b.x >> (8 * q)) & 7u) << (3 * q);
    #pragma unroll
    for (int q = 0; q < 4; ++q) fn |= ((b.y >> (8 * q)) & 7u) << (3 * (q + 4));
    f[i] = fn;
    F = fn_compose(fn, F);
  }
  sc[tid] = F;
  __syncthreads();
  #pragma unroll
  for (int d = 1; d < 1024; d <<= 1) {
    unsigned int v = sc[tid];
    unsigned int p = (tid >= d) ? sc[tid - d] : 0u;
    unsigned int nv = (tid >= d) ? fn_compose(v, p) : v;
    __syncthreads();
    sc[tid] = nv;
    __syncthreads();
  }
  unsigned int E = (tid == 0) ? IDENT : sc[tid - 1];
  unsigned int state = E & 7u;
  bool mine = (tid >> 3) == bid;
  #pragma unroll
  for (int i = 0; i < 16; ++i) {
    int tt = t0 + i;
    unsigned int nx = (f[i] >> (3 * state)) & 7u;
    if (mine) {
      cur_s[tt - bid * 128] = (unsigned char)state;
      d_out[131072 + tt] = (float)nx;
    }
    state = nx;
  }
  __syncthreads();
  int idx = bid * 1024 + tid;              // < 131072
  int t = idx >> 3, z = idx & 7;
  int cur = (int)cur_s[t - bid * 128];
  int tile = t >> 6;
  int blk2 = cur * 256 + tile;
  int flag = crx[blk2 * 24 + 9];
  float val;
  if (flag == 1) {
    float frac = (float)(t & 63) * (1.0f / 63.0f);
    float L = a4lr[blk2 * 16 + z];
    float R = a4lr[blk2 * 16 + 8 + z];
    float a4 = fmaf(frac, R - L, L);
    val = fmaf(0.2f, dv[(size_t)t * 8 + z], a4) - pen[cur * 8 + z];
  } else {
    val = ws[WS_CONS + ((size_t)t * 8 + cur) * 8 + z];
  }
  d_out[idx] = val;
}

extern "C" void kernel_launch(void* const* d_in, const int* in_sizes, int n_in,
                              void* d_out, int out_size, void* d_ws, size_t ws_size,
                              hipStream_t stream) {
  const float* pa    = (const float*)d_in[0];
  const float* times = (const float*)d_in[1];
  const float* gum   = (const float*)d_in[2];
  const int*   edge  = (const int*)d_in[3];
  const float* W1  = (const float*)d_in[4];
  const float* b1  = (const float*)d_in[5];
  const float* W2  = (const float*)d_in[6];
  const float* b2  = (const float*)d_in[7];
  const float* W3  = (const float*)d_in[8];
  const float* b3  = (const float*)d_in[9];
  const float* W4  = (const float*)d_in[10];
  const float* b4  = (const float*)d_in[11];
  const float* D1  = (const float*)d_in[12];
  const float* d1v = (const float*)d_in[13];
  const float* D2  = (const float*)d_in[14];
  const float* d2v = (const float*)d_in[15];
  const float* D3  = (const float*)d_in[16];
  const float* d3v = (const float*)d_in[17];
  const float* tau = (const float*)d_in[18];
  float* ws = (float*)d_ws;
  float* out = (float*)d_out;
  int* crx = (int*)((char*)d_ws + WSB_CRX);

  k_prepdiv<<<NB_PREP, 256, 0, stream>>>(pa, times, gum, edge, W1, b1, W2, W3, W4,
                                         D1, d1v, D2, d2v, D3, d3v, ws);
  k_ab4<<<2048, 256, 0, stream>>>(times, ws + WS_U, ws + WS_V, ws + WS_W1ZT,
                                  ws + WS_W2T, ws + WS_W3T, ws + WS_W4T,
                                  b2, b3, b4, ws + WS_ABT, crx,
                                  ws + WS_A4LR, ws + WS_H3LR);
  k_mlp<<<2048, 256, 0, stream>>>(times, ws + WS_U, ws + WS_V, ws + WS_W1ZT,
                                  ws + WS_W2T, ws + WS_ABT, crx,
                                  ws + WS_A4LR, ws + WS_H3LR,
                                  ws + WS_W3T, ws + WS_W4T, b2, b3, b4,
                                  ws + WS_DV, ws + WS_G, ws + WS_PEN, tau,
                                  ws + WS_CONS, (unsigned char*)ws + WSB_NXT8);
  k_scangather<<<128, 1024, 0, stream>>>(ws, crx, ws + WS_A4LR, ws + WS_DV,
                                         ws + WS_PEN, out);
}